// Round 10
// baseline (162.769 us; speedup 1.0000x reference)
//
#include <hip/hip_runtime.h>
#include <hip/hip_bf16.h>
#include <stdint.h>

// ---------- types & helpers ----------
typedef __attribute__((ext_vector_type(4))) float f32x4;
typedef __attribute__((ext_vector_type(8))) short s16x8;
typedef __attribute__((ext_vector_type(4))) short s16x4;
typedef __attribute__((ext_vector_type(8))) __bf16 b16x8;

__device__ __forceinline__ f32x4 mfma16(s16x8 a, s16x8 b, f32x4 c) {
  return __builtin_amdgcn_mfma_f32_16x16x32_bf16(
      __builtin_bit_cast(b16x8, a), __builtin_bit_cast(b16x8, b), c, 0, 0, 0);
}

__device__ __forceinline__ void gl_lds16(const void* g, void* l) {
  __builtin_amdgcn_global_load_lds(
      (const __attribute__((address_space(1))) void*)g,
      (__attribute__((address_space(3))) void*)l, 16, 0, 0);
}

__device__ __forceinline__ unsigned short f2bf(float f) {
  union { float f; unsigned u; } v; v.f = f;
  unsigned u = v.u;
  return (unsigned short)((u + 0x7FFFu + ((u >> 16) & 1u)) >> 16);
}

__device__ __forceinline__ float bf2f(unsigned short u) {
  union { unsigned u; float f; } v; v.u = ((unsigned)u) << 16; return v.f;
}

__device__ __forceinline__ unsigned cvt_pk_bf16(float a, float b) {
  unsigned r;
  asm("v_cvt_pk_bf16_f32 %0, %1, %2" : "=v"(r) : "v"(a), "v"(b));
  return r;
}

#if __has_builtin(__builtin_amdgcn_exp2f)
#define EXP2F(x) __builtin_amdgcn_exp2f(x)
#else
#define EXP2F(x) exp2f(x)
#endif

// B pre-fragment offset: n_f=n>>4, r=n&15, kc=k>>5, g=(k>>3)&3, j=k&7
__device__ __forceinline__ int bfrag_off(int n, int k) {
  return ((((n >> 4) * 16 + (k >> 5)) * 4 + ((k >> 3) & 3)) * 16 + (n & 15)) * 8 + (k & 7);
}

// ---------- K1: gather x -> blocked layout + LN1; blocks >=1024 do weight prep ----------
__global__ __launch_bounds__(256) void k_gather_ln(
    const float* __restrict__ x, const float* __restrict__ g1, const float* __restrict__ b1,
    unsigned short* __restrict__ xb, unsigned short* __restrict__ xn,
    const float* __restrict__ wq, const float* __restrict__ wk, const float* __restrict__ wv,
    const float* __restrict__ wp, const float* __restrict__ w1, const float* __restrict__ w2,
    unsigned short* __restrict__ qkvT, unsigned short* __restrict__ wpT,
    unsigned short* __restrict__ w1T, unsigned short* __restrict__ w2T)
{
  if (blockIdx.x >= 1024) {            // ---- weight prep path (pre-fragmented B) ----
    int i = (blockIdx.x - 1024) * 256 + threadIdx.x;
    if (i < 786432) {
      int n = i >> 9, d = i & 511;
      const float* src = (n < 512) ? wq : (n < 1024 ? wk : wv);
      int nn = n & 511;
      int h = nn >> 6, e = nn & 63;
      qkvT[bfrag_off(n, d)] = f2bf(src[((size_t)h * 512 + d) * 64 + e]);
    } else {
      int j = i - 786432;
      int w = j >> 18;
      int o = j & 262143;
      const float* s = (w == 0) ? wp : (w == 1 ? w1 : w2);
      unsigned short* dst = (w == 0) ? wpT : (w == 1 ? w1T : w2T);
      dst[bfrag_off(o >> 9, o & 511)] = f2bf(s[o]);
    }
    return;
  }
  __shared__ float lx[16][517];
  int gid = blockIdx.x;
  int h2 = gid & 1, hh = (gid >> 1) & 7, tt = (gid >> 4) & 3,
      shI = (gid >> 6) & 3, stI = (gid >> 8) & 1, bI = (gid >> 9) & 1;
  const float* xbase = x + (size_t)bI * 4194304 + (size_t)(stI * 4 + tt) * 1024
                       + (shI * 8 + hh) * 32 + h2 * 16;
  int t = threadIdx.x;
  for (int i = 0; i < 8; ++i) {
    int slot = i * 256 + t;
    int c = slot >> 2, w8 = slot & 3;
    const float4 v = *(const float4*)(xbase + (size_t)c * 8192 + w8 * 4);
    lx[w8 * 4 + 0][c] = v.x; lx[w8 * 4 + 1][c] = v.y;
    lx[w8 * 4 + 2][c] = v.z; lx[w8 * 4 + 3][c] = v.w;
  }
  __syncthreads();
  int lane = t & 63, wid = t >> 6;
  for (int q = 0; q < 4; ++q) {
    int widx = wid * 4 + q;
    float vv[8]; float s = 0.f, ss = 0.f;
    #pragma unroll
    for (int i = 0; i < 8; ++i) { float v = lx[widx][lane + i * 64]; vv[i] = v; s += v; ss += v * v; }
    #pragma unroll
    for (int d = 1; d < 64; d <<= 1) { s += __shfl_xor(s, d); ss += __shfl_xor(ss, d); }
    float mean = s * (1.f / 512.f);
    float var = ss * (1.f / 512.f) - mean * mean;
    float rs = rsqrtf(var + 1e-5f);
    int sw = h2 * 2 + (widx >> 3), ww = widx & 7;
    int blk = ((bI * 2 + stI) * 4 + shI) * 4 + sw;
    int n = tt * 64 + hh * 8 + ww;
    size_t base = ((size_t)blk * 256 + n) * 512;
    #pragma unroll
    for (int i = 0; i < 8; ++i) {
      int c = lane + i * 64;
      float v = vv[i];
      xb[base + c] = f2bf(v);
      xn[base + c] = f2bf((v - mean) * rs * g1[c] + b1[c]);
    }
  }
}

// ---------- GEMM: 2 m-tiles per WG (amortize prologue/epilogue), R7-proven inner loop ----------
// Each WG: 256 rows (2 x 128-row tiles sequential, same n-panel -> B L2-hot).
// Counted vmcnt(4); at t=1 iter0 it also retires t=0's epilogue stores (conservative, safe).
// gridDim.x MUST be 64. EPI: 0 = QKV (bf16 + V transposed)  1 = proj (+bf16 resid -> bf16)
//      2 = FFN1 (+bias, relu, bf16)  3 = FFN2 (+bias +bf16 addf, f32 direct scatter to out)
template<int EPI>
__global__ __launch_bounds__(256, 2) void k_gemm(
    const unsigned short* __restrict__ A, const unsigned short* __restrict__ Bt,
    int M, int N,
    unsigned short* __restrict__ Cbf, float* __restrict__ Cf,
    const float* __restrict__ bias,
    const unsigned short* __restrict__ addbf,
    unsigned short* __restrict__ vTout)
{
  constexpr int K = 512;
  __shared__ __align__(16) unsigned short a_lds[2][128 * 64];
  int tid = threadIdx.x, lane = tid & 63, wid = tid >> 6;
  int lin = blockIdx.y * gridDim.x + blockIdx.x;
  int xcd = lin & 7, idx = lin >> 3;
  int bx = xcd * 8 + (idx & 7);     // gridDim.x == 64; per-XCD A-chunk = 2MB
  int by = idx >> 3;
  int m0base = bx * 256, n0 = by * 128;
  int wm = (wid >> 1) * 64, wn = (wid & 1) * 64;
  int r15 = lane & 15, g = lane >> 4;
  int g4 = g * 4;

  // B fragment base (same n-panel for both tiles)
  const unsigned short* bfbase = Bt + (size_t)((n0 + wn) >> 4) * 8192 + lane * 8;

  #pragma unroll
  for (int t = 0; t < 2; ++t) {
    int m0 = m0base + t * 128;
    const unsigned short* aptr[4];
    int segoff[4];
    #pragma unroll
    for (int s = 0; s < 4; ++s) {
      int seg = wid * 4 + s;
      int slot = seg * 64 + lane;
      int m = slot >> 3, lc = (slot & 7) ^ (m & 7);
      aptr[s] = A + (size_t)(m0 + m) * K + lc * 8;
      segoff[s] = seg * 1024;
    }

    f32x4 acc[4][4] = {};
    s16x8 b[2][4][2];

    // prologue: stage A(0), load B(0)
    #pragma unroll
    for (int s = 0; s < 4; ++s) gl_lds16(aptr[s], (char*)a_lds[0] + segoff[s]);
    #pragma unroll
    for (int f = 0; f < 4; ++f)
      #pragma unroll
      for (int kk = 0; kk < 2; ++kk)
        b[0][f][kk] = *(const s16x8*)(bfbase + f * 8192 + kk * 512);

    #pragma unroll
    for (int it = 0; it < 8; ++it) {
      int cur = it & 1;
      if (it < 7) {
        int ksn = (it + 1) * 64;
        #pragma unroll
        for (int s = 0; s < 4; ++s)
          gl_lds16(aptr[s] + ksn, (char*)a_lds[cur ^ 1] + segoff[s]);
        asm volatile("s_waitcnt vmcnt(4)" ::: "memory");   // A(it)+B(it) retired
      } else {
        asm volatile("s_waitcnt vmcnt(0)" ::: "memory");
      }
      __builtin_amdgcn_s_barrier();
      __builtin_amdgcn_sched_barrier(0);
      if (it < 7) {                      // B(it+1) -> regs, hidden under MFMA
        int kc0 = (it + 1) * 2;
        #pragma unroll
        for (int f = 0; f < 4; ++f)
          #pragma unroll
          for (int kk = 0; kk < 2; ++kk)
            b[cur ^ 1][f][kk] = *(const s16x8*)(bfbase + f * 8192 + (kc0 + kk) * 512);
      }
      const char* al = (const char*)a_lds[cur];
      #pragma unroll
      for (int kk = 0; kk < 2; ++kk) {
        s16x8 af[4];
        #pragma unroll
        for (int f = 0; f < 4; ++f) {
          int mm = wm + f * 16 + r15;
          af[f] = *(const s16x8*)(al + mm * 128 + (((kk * 4 + g) ^ (mm & 7)) * 16));
        }
        __builtin_amdgcn_s_setprio(1);
        #pragma unroll
        for (int fm = 0; fm < 4; ++fm)
          #pragma unroll
          for (int fn = 0; fn < 4; ++fn)
            acc[fm][fn] = mfma16(af[fm], b[cur][fn][kk], acc[fm][fn]);
        __builtin_amdgcn_s_setprio(0);
      }
      __builtin_amdgcn_s_barrier();      // a_lds[cur] consumed -> reusable
      __builtin_amdgcn_sched_barrier(0);
    }

    // epilogue for this m-tile (stores overlap next tile's prologue)
    #pragma unroll
    for (int fm = 0; fm < 4; ++fm) {
      #pragma unroll
      for (int fn = 0; fn < 4; ++fn) {
        int col = n0 + wn + fn * 16 + r15;
        int row0 = m0 + wm + fm * 16 + g4;
        if (EPI == 0 && col >= 1024) {
          int h = (col - 1024) >> 6, e = col & 63;
          int blk = row0 >> 8, mtok = row0 & 255;
          s16x4 pk;
          #pragma unroll
          for (int r = 0; r < 4; ++r) pk[r] = (short)f2bf(acc[fm][fn][r]);
          *(s16x4*)(vTout + (((size_t)blk * 8 + h) * 64 + e) * 256 + mtok) = pk;
        } else if (EPI == 3) {
          int blk = row0 >> 8, tok0 = row0 & 255;
          int sw = blk & 3, shI = (blk >> 2) & 3, stI = (blk >> 4) & 1, bI = blk >> 5;
          int tt = tok0 >> 6, hh = (tok0 >> 3) & 7, ww0 = tok0 & 7;
          size_t addr = (size_t)bI * 4194304 + (size_t)col * 8192
                      + (size_t)(stI * 4 + tt) * 1024 + (shI * 8 + hh) * 32 + sw * 8 + ww0;
          float4 o;
          float bb = bias[col];
          o.x = acc[fm][fn][0] + bb + bf2f(addbf[(size_t)(row0 + 0) * 512 + col]);
          o.y = acc[fm][fn][1] + bb + bf2f(addbf[(size_t)(row0 + 1) * 512 + col]);
          o.z = acc[fm][fn][2] + bb + bf2f(addbf[(size_t)(row0 + 2) * 512 + col]);
          o.w = acc[fm][fn][3] + bb + bf2f(addbf[(size_t)(row0 + 3) * 512 + col]);
          *(float4*)(Cf + addr) = o;
        } else {
          #pragma unroll
          for (int r = 0; r < 4; ++r) {
            int row = row0 + r;
            float v = acc[fm][fn][r];
            if (EPI == 0) {
              Cbf[(size_t)row * 1536 + col] = f2bf(v);
            } else if (EPI == 1) {
              Cbf[(size_t)row * 512 + col] = f2bf(v + bf2f(addbf[(size_t)row * 512 + col]));
            } else if (EPI == 2) {
              Cbf[(size_t)row * 512 + col] = f2bf(fmaxf(v + bias[col], 0.f));
            }
          }
        }
      }
    }
  }
}

// ---------- K3: block-local attention, counted-vmcnt double-buffered staging ----------
__global__ __launch_bounds__(256, 1) void k_attn(
    const unsigned short* __restrict__ qkv, const unsigned short* __restrict__ vT,
    const float* __restrict__ dtb, const float* __restrict__ dhb, const float* __restrict__ dwb,
    unsigned short* __restrict__ aout)
{
  __shared__ __align__(16) unsigned short k_lds[2][64 * 64];
  __shared__ __align__(16) unsigned short v_lds[2][64 * 64];
  __shared__ __align__(16) unsigned short p_lds[4][64 * 64];
  __shared__ float bt_s[8], bh_s[16], bw_s[16];

  const float L2E = 1.44269504f;
  const float SC = 0.125f * 1.44269504f;   // 1/sqrt(64) * log2(e)

  int tid = threadIdx.x, lane = tid & 63, wid = tid >> 6;
  int bk = blockIdx.x >> 3, h = blockIdx.x & 7;
  if (tid < 7) bt_s[tid] = dtb[h * 7 + tid] * L2E;
  else if (tid < 22) bh_s[tid - 7] = dhb[h * 15 + tid - 7] * L2E;
  else if (tid < 37) bw_s[tid - 22] = dwb[h * 15 + tid - 22] * L2E;

  int r15 = lane & 15, g = lane >> 4;
  int wq0 = wid * 64;
  size_t bkBase = (size_t)bk * 256;
  const unsigned short* kbase = qkv + 512 + h * 64;
  const unsigned short* vbase = vT + ((size_t)bk * 8 + h) * 64 * 256;

  // Q fragments, resident (B-operand: lane r15 = q-row, g = k-octet)
  s16x8 qf[4][2];
  #pragma unroll
  for (int fn = 0; fn < 4; ++fn)
    #pragma unroll
    for (int kk = 0; kk < 2; ++kk)
      qf[fn][kk] = *(const s16x8*)(qkv + (bkBase + wq0 + fn * 16 + r15) * 1536
                                   + h * 64 + kk * 32 + g * 8);

  float btoff[4], hb[7], wb[4];

  // ---- stage mt=0 into buffer 0, then full-drain barrier (covers bias tables too) ----
  #pragma unroll
  for (int s = 0; s < 4; ++s) {
    int sg = wid * 4 + s;
    if (sg < 8) {
      int slot = sg * 64 + lane;
      int m = slot >> 3, lc = (slot & 7) ^ (m & 7);
      gl_lds16(kbase + (bkBase + m) * 1536 + lc * 8, (char*)(&k_lds[0][0]) + sg * 1024);
    } else {
      int sg2 = sg - 8;
      int slot = sg2 * 64 + lane;
      int e = slot >> 3, lc = (slot & 7) ^ (e & 7);
      gl_lds16(vbase + (size_t)e * 256 + lc * 8, (char*)(&v_lds[0][0]) + sg2 * 1024);
    }
  }
  __syncthreads();

  {
    int Dh = (r15 >> 3) - (g >> 1) + 7;
    int Wb = (r15 & 7) - 4 * (g & 1) + 7;
    #pragma unroll
    for (int mt = 0; mt < 4; ++mt) btoff[mt] = bt_s[wid + 3 - mt];
    #pragma unroll
    for (int d = 0; d < 7; ++d) hb[d] = bh_s[Dh + 2 * d - 6];
    #pragma unroll
    for (int r = 0; r < 4; ++r) wb[r] = bw_s[Wb - r];
  }

  f32x4 o[4][4] = {};                       // o[fe][fn] : O^T[e][n]
  float mrun[4] = {-1e30f, -1e30f, -1e30f, -1e30f};
  float lrun[4] = {0.f, 0.f, 0.f, 0.f};
  char* p_w = (char*)(&p_lds[wid][0]);

  #pragma unroll
  for (int mt = 0; mt < 4; ++mt) {
    int cur = mt & 1;
    if (mt < 3) {
      int m0n = (mt + 1) * 64;
      #pragma unroll
      for (int s = 0; s < 4; ++s) {
        int sg = wid * 4 + s;
        if (sg < 8) {
          int slot = sg * 64 + lane;
          int m = slot >> 3, lc = (slot & 7) ^ (m & 7);
          gl_lds16(kbase + (bkBase + m0n + m) * 1536 + lc * 8,
                   (char*)(&k_lds[cur ^ 1][0]) + sg * 1024);
        } else {
          int sg2 = sg - 8;
          int slot = sg2 * 64 + lane;
          int e = slot >> 3, lc = (slot & 7) ^ (e & 7);
          gl_lds16(vbase + (size_t)e * 256 + m0n + lc * 8,
                   (char*)(&v_lds[cur ^ 1][0]) + sg2 * 1024);
        }
      }
    }
    if (mt > 0) {
      if (mt < 3) asm volatile("s_waitcnt vmcnt(4)" ::: "memory");
      else        asm volatile("s_waitcnt vmcnt(0)" ::: "memory");
      __builtin_amdgcn_s_barrier();
      __builtin_amdgcn_sched_barrier(0);
    }
    const char* kl = (const char*)(&k_lds[cur][0]);
    const char* vl = (const char*)(&v_lds[cur][0]);

    // S^T[m][n] = sum_e K[m][e] Q[n][e]
    f32x4 st[4][4] = {};
    #pragma unroll
    for (int kk = 0; kk < 2; ++kk) {
      s16x8 kf[4];
      #pragma unroll
      for (int fm = 0; fm < 4; ++fm) {
        int m = fm * 16 + r15;
        kf[fm] = *(const s16x8*)(kl + m * 128 + (((kk * 4 + g) ^ (m & 7)) * 16));
      }
      __builtin_amdgcn_s_setprio(1);
      #pragma unroll
      for (int fm = 0; fm < 4; ++fm)
        #pragma unroll
        for (int fn = 0; fn < 4; ++fn)
          st[fm][fn] = mfma16(kf[fm], qf[fn][kk], st[fm][fn]);
      __builtin_amdgcn_s_setprio(0);
    }

    // online softmax in exp2 domain
    #pragma unroll
    for (int fn = 0; fn < 4; ++fn) {
      float vals[16];
      float mx = -1e30f;
      #pragma unroll
      for (int fm = 0; fm < 4; ++fm) {
        float cc = btoff[mt] + hb[fn - fm + 3];
        #pragma unroll
        for (int r = 0; r < 4; ++r) {
          float v = fmaf(st[fm][fn][r], SC, cc) + wb[r];
          vals[fm * 4 + r] = v;
          mx = fmaxf(mx, v);
        }
      }
      mx = fmaxf(mx, __shfl_xor(mx, 16));
      mx = fmaxf(mx, __shfl_xor(mx, 32));
      if (!__all(mx <= mrun[fn] + 8.f)) {       // T13 defer-rescale
        float mnew = fmaxf(mrun[fn], mx);
        float al = EXP2F(mrun[fn] - mnew);
        mrun[fn] = mnew;
        lrun[fn] *= al;
        #pragma unroll
        for (int fe = 0; fe < 4; ++fe)
          #pragma unroll
          for (int r = 0; r < 4; ++r)
            o[fe][fn][r] *= al;
      }
      float m_c = mrun[fn];
      float p[16]; float sum = 0.f;
      #pragma unroll
      for (int i = 0; i < 16; ++i) { p[i] = EXP2F(vals[i] - m_c); sum += p[i]; }
      sum += __shfl_xor(sum, 16);
      sum += __shfl_xor(sum, 32);
      lrun[fn] += sum;
      int nl = fn * 16 + r15;
      char* prow = p_w + nl * 128 + (g & 1) * 8;
      #pragma unroll
      for (int fm = 0; fm < 4; ++fm) {
        unsigned u0 = cvt_pk_bf16(p[fm * 4 + 0], p[fm * 4 + 1]);
        unsigned u1 = cvt_pk_bf16(p[fm * 4 + 2], p[fm * 4 + 3]);
        int lc = fm * 2 + (g >> 1);
        *(uint2*)(prow + ((lc ^ (nl & 7)) * 16)) = make_uint2(u0, u1);
      }
    }
    asm volatile("s_waitcnt lgkmcnt(0)" ::: "memory");
    __builtin_amdgcn_sched_barrier(0);

    // O^T += V^T * P^T
    #pragma unroll
    for (int mm = 0; mm < 2; ++mm) {
      s16x8 vf[4], pf[4];
      #pragma unroll
      for (int fe = 0; fe < 4; ++fe) {
        int e = fe * 16 + r15;
        vf[fe] = *(const s16x8*)(vl + e * 128 + (((mm * 4 + g) ^ (e & 7)) * 16));
      }
      #pragma unroll
      for (int fn = 0; fn < 4; ++fn) {
        int nl = fn * 16 + r15;
        pf[fn] = *(const s16x8*)(p_w + nl * 128 + (((mm * 4 + g) ^ (nl & 7)) * 16));
      }
      __builtin_amdgcn_s_setprio(1);
      #pragma unroll
      for (int fe = 0; fe < 4; ++fe)
        #pragma unroll
        for (int fn = 0; fn < 4; ++fn)
          o[fe][fn] = mfma16(vf[fe], pf[fn], o[fe][fn]);
      __builtin_amdgcn_s_setprio(0);
    }
    __builtin_amdgcn_s_barrier();
    __builtin_amdgcn_sched_barrier(0);
  }

  // epilogue: direct 8B stores
  #pragma unroll
  for (int fn = 0; fn < 4; ++fn) {
    float inv = 1.f / lrun[fn];
    size_t rowb = (bkBase + wq0 + fn * 16 + r15) * 512 + h * 64;
    #pragma unroll
    for (int fe = 0; fe < 4; ++fe) {
      unsigned u0 = cvt_pk_bf16(o[fe][fn][0] * inv, o[fe][fn][1] * inv);
      unsigned u1 = cvt_pk_bf16(o[fe][fn][2] * inv, o[fe][fn][3] * inv);
      *(uint2*)(aout + rowb + fe * 16 + g * 4) = make_uint2(u0, u1);
    }
  }
}

// ---------- K5: LN2 (rowwise over 512), bf16 in -> bf16 out ----------
__global__ __launch_bounds__(256) void k_ln2(
    const unsigned short* __restrict__ in, const float* __restrict__ g2, const float* __restrict__ b2,
    unsigned short* __restrict__ out)
{
  int token = blockIdx.x * 4 + (threadIdx.x >> 6);
  int lane = threadIdx.x & 63;
  s16x8 v8 = *(const s16x8*)(in + (size_t)token * 512 + lane * 8);
  float vv[8]; float s = 0.f, ss = 0.f;
  #pragma unroll
  for (int i = 0; i < 8; ++i) {
    float v = bf2f((unsigned short)v8[i]); vv[i] = v; s += v; ss += v * v;
  }
  #pragma unroll
  for (int d = 1; d < 64; d <<= 1) { s += __shfl_xor(s, d); ss += __shfl_xor(ss, d); }
  float mean = s * (1.f / 512.f);
  float var = ss * (1.f / 512.f) - mean * mean;
  float rs = rsqrtf(var + 1e-5f);
  const float4 gA = *(const float4*)(g2 + lane * 8);
  const float4 gB = *(const float4*)(g2 + lane * 8 + 4);
  const float4 bA = *(const float4*)(b2 + lane * 8);
  const float4 bB = *(const float4*)(b2 + lane * 8 + 4);
  float gv[8] = {gA.x, gA.y, gA.z, gA.w, gB.x, gB.y, gB.z, gB.w};
  float bv[8] = {bA.x, bA.y, bA.z, bA.w, bB.x, bB.y, bB.z, bB.w};
  s16x8 o8;
  #pragma unroll
  for (int i = 0; i < 8; ++i)
    o8[i] = (short)f2bf((vv[i] - mean) * rs * gv[i] + bv[i]);
  *(s16x8*)(out + (size_t)token * 512 + lane * 8) = o8;
}

// ---------- host ----------
extern "C" void kernel_launch(void* const* d_in, const int* in_sizes, int n_in,
                              void* d_out, int out_size, void* d_ws, size_t ws_size,
                              hipStream_t stream)
{
  const float* x   = (const float*)d_in[0];
  const float* dtb = (const float*)d_in[1];
  const float* dhb = (const float*)d_in[2];
  const float* dwb = (const float*)d_in[3];
  const float* g1  = (const float*)d_in[4];
  const float* bb1 = (const float*)d_in[5];
  const float* wq  = (const float*)d_in[6];
  const float* wk  = (const float*)d_in[7];
  const float* wv  = (const float*)d_in[8];
  const float* wp  = (const float*)d_in[9];
  const float* g2  = (const float*)d_in[10];
  const float* bb2 = (const float*)d_in[11];
  const float* w1  = (const float*)d_in[12];
  const float* fb1 = (const float*)d_in[13];
  const float* w2  = (const float*)d_in[14];
  const float* fb2 = (const float*)d_in[15];

  char* ws = (char*)d_ws;
  unsigned short* xb   = (unsigned short*)(ws + 0);          // resid bf16 [K1..gemm1]
  unsigned short* vT   = (unsigned short*)(ws + 33554432);   // v^T bf16 [gemm0..attn]
  unsigned short* out1b= (unsigned short*)(ws + 33554432);   // proj+resid bf16 [gemm1..gemm3]
  unsigned short* qkv  = (unsigned short*)(ws + 67108864);   // q,k bf16 [gemm0..attn]; h1 [gemm2..gemm3]
  unsigned short* xn   = (unsigned short*)(ws + 117440512);  // xn; attn_out; y
  unsigned short* qkvT = (unsigned short*)(ws + 134217728);
  unsigned short* wpT  = (unsigned short*)(ws + 135790592);
  unsigned short* w1T  = (unsigned short*)(ws + 136314880);
  unsigned short* w2T  = (unsigned short*)(ws + 136839168);

  unsigned short* attn_out = xn;
  unsigned short* yb = xn;
  unsigned short* h1 = qkv;
  float* outp = (float*)d_out;

  k_gather_ln<<<1024 + 6144, 256, 0, stream>>>(x, g1, bb1, xb, xn,
      wq, wk, wv, wp, w1, w2, qkvT, wpT, w1T, w2T);
  k_gemm<0><<<dim3(64, 12), 256, 0, stream>>>(xn, qkvT, 16384, 1536, qkv, nullptr, nullptr, nullptr, vT);
  k_attn<<<512, 256, 0, stream>>>(qkv, vT, dtb, dhb, dwb, attn_out);
  k_gemm<1><<<dim3(64, 4), 256, 0, stream>>>(attn_out, wpT, 16384, 512, out1b, nullptr, nullptr, xb, nullptr);
  k_ln2<<<4096, 256, 0, stream>>>(out1b, g2, bb2, yb);
  k_gemm<2><<<dim3(64, 4), 256, 0, stream>>>(yb, w1T, 16384, 512, h1, nullptr, fb1, nullptr, nullptr);
  k_gemm<3><<<dim3(64, 4), 256, 0, stream>>>(h1, w2T, 16384, 512, nullptr, outp, fb2, out1b, nullptr);
}

// Round 11
// 156.947 us; speedup vs baseline: 1.0371x; 1.0371x over previous
//
#include <hip/hip_runtime.h>
#include <hip/hip_bf16.h>
#include <stdint.h>

// ---------- types & helpers ----------
typedef __attribute__((ext_vector_type(4))) float f32x4;
typedef __attribute__((ext_vector_type(8))) short s16x8;
typedef __attribute__((ext_vector_type(4))) short s16x4;
typedef __attribute__((ext_vector_type(8))) __bf16 b16x8;

__device__ __forceinline__ f32x4 mfma16(s16x8 a, s16x8 b, f32x4 c) {
  return __builtin_amdgcn_mfma_f32_16x16x32_bf16(
      __builtin_bit_cast(b16x8, a), __builtin_bit_cast(b16x8, b), c, 0, 0, 0);
}

__device__ __forceinline__ void gl_lds16(const void* g, void* l) {
  __builtin_amdgcn_global_load_lds(
      (const __attribute__((address_space(1))) void*)g,
      (__attribute__((address_space(3))) void*)l, 16, 0, 0);
}

__device__ __forceinline__ unsigned short f2bf(float f) {
  union { float f; unsigned u; } v; v.f = f;
  unsigned u = v.u;
  return (unsigned short)((u + 0x7FFFu + ((u >> 16) & 1u)) >> 16);
}

__device__ __forceinline__ float bf2f(unsigned short u) {
  union { unsigned u; float f; } v; v.u = ((unsigned)u) << 16; return v.f;
}

__device__ __forceinline__ unsigned cvt_pk_bf16(float a, float b) {
  unsigned r;
  asm("v_cvt_pk_bf16_f32 %0, %1, %2" : "=v"(r) : "v"(a), "v"(b));
  return r;
}

#if __has_builtin(__builtin_amdgcn_exp2f)
#define EXP2F(x) __builtin_amdgcn_exp2f(x)
#else
#define EXP2F(x) exp2f(x)
#endif

// B pre-fragment offset: n_f=n>>4, r=n&15, kc=k>>5, g=(k>>3)&3, j=k&7
__device__ __forceinline__ int bfrag_off(int n, int k) {
  return ((((n >> 4) * 16 + (k >> 5)) * 4 + ((k >> 3) & 3)) * 16 + (n & 15)) * 8 + (k & 7);
}

// ---------- K1: gather x -> blocked layout + LN1; blocks >=1024 do weight prep ----------
__global__ __launch_bounds__(256) void k_gather_ln(
    const float* __restrict__ x, const float* __restrict__ g1, const float* __restrict__ b1,
    unsigned short* __restrict__ xb, unsigned short* __restrict__ xn,
    const float* __restrict__ wq, const float* __restrict__ wk, const float* __restrict__ wv,
    const float* __restrict__ wp, const float* __restrict__ w1, const float* __restrict__ w2,
    unsigned short* __restrict__ qkvT, unsigned short* __restrict__ wpT,
    unsigned short* __restrict__ w1T, unsigned short* __restrict__ w2T)
{
  if (blockIdx.x >= 1024) {            // ---- weight prep path (pre-fragmented B) ----
    int i = (blockIdx.x - 1024) * 256 + threadIdx.x;
    if (i < 786432) {
      int n = i >> 9, d = i & 511;
      const float* src = (n < 512) ? wq : (n < 1024 ? wk : wv);
      int nn = n & 511;
      int h = nn >> 6, e = nn & 63;
      qkvT[bfrag_off(n, d)] = f2bf(src[((size_t)h * 512 + d) * 64 + e]);
    } else {
      int j = i - 786432;
      int w = j >> 18;
      int o = j & 262143;
      const float* s = (w == 0) ? wp : (w == 1 ? w1 : w2);
      unsigned short* dst = (w == 0) ? wpT : (w == 1 ? w1T : w2T);
      dst[bfrag_off(o >> 9, o & 511)] = f2bf(s[o]);
    }
    return;
  }
  __shared__ float lx[16][517];
  int gid = blockIdx.x;
  int h2 = gid & 1, hh = (gid >> 1) & 7, tt = (gid >> 4) & 3,
      shI = (gid >> 6) & 3, stI = (gid >> 8) & 1, bI = (gid >> 9) & 1;
  const float* xbase = x + (size_t)bI * 4194304 + (size_t)(stI * 4 + tt) * 1024
                       + (shI * 8 + hh) * 32 + h2 * 16;
  int t = threadIdx.x;
  for (int i = 0; i < 8; ++i) {
    int slot = i * 256 + t;
    int c = slot >> 2, w8 = slot & 3;
    const float4 v = *(const float4*)(xbase + (size_t)c * 8192 + w8 * 4);
    lx[w8 * 4 + 0][c] = v.x; lx[w8 * 4 + 1][c] = v.y;
    lx[w8 * 4 + 2][c] = v.z; lx[w8 * 4 + 3][c] = v.w;
  }
  __syncthreads();
  int lane = t & 63, wid = t >> 6;
  for (int q = 0; q < 4; ++q) {
    int widx = wid * 4 + q;
    float vv[8]; float s = 0.f, ss = 0.f;
    #pragma unroll
    for (int i = 0; i < 8; ++i) { float v = lx[widx][lane + i * 64]; vv[i] = v; s += v; ss += v * v; }
    #pragma unroll
    for (int d = 1; d < 64; d <<= 1) { s += __shfl_xor(s, d); ss += __shfl_xor(ss, d); }
    float mean = s * (1.f / 512.f);
    float var = ss * (1.f / 512.f) - mean * mean;
    float rs = rsqrtf(var + 1e-5f);
    int sw = h2 * 2 + (widx >> 3), ww = widx & 7;
    int blk = ((bI * 2 + stI) * 4 + shI) * 4 + sw;
    int n = tt * 64 + hh * 8 + ww;
    size_t base = ((size_t)blk * 256 + n) * 512;
    #pragma unroll
    for (int i = 0; i < 8; ++i) {
      int c = lane + i * 64;
      float v = vv[i];
      xb[base + c] = f2bf(v);
      xn[base + c] = f2bf((v - mean) * rs * g1[c] + b1[c]);
    }
  }
}

// ---------- GEMM (R7/R9-proven): 128x128 tile, A via LDS dbuf, B pre-frag via L2->regs ----------
// gridDim.x MUST be 128.
// EPI: 1 = proj (+bf16 resid -> bf16)  2 = FFN1 (+bias, relu, bf16)
//      3 = FFN2 (+bias +bf16 addf, f32 direct scatter to (B,C,T,H,W))
template<int EPI>
__global__ __launch_bounds__(256, 2) void k_gemm(
    const unsigned short* __restrict__ A, const unsigned short* __restrict__ Bt,
    int M, int N,
    unsigned short* __restrict__ Cbf, float* __restrict__ Cf,
    const float* __restrict__ bias,
    const unsigned short* __restrict__ addbf,
    unsigned short* __restrict__ vTout)
{
  constexpr int K = 512;
  __shared__ __align__(16) unsigned short a_lds[2][128 * 64];
  int tid = threadIdx.x, lane = tid & 63, wid = tid >> 6;
  int lin = blockIdx.y * gridDim.x + blockIdx.x;
  int xcd = lin & 7, idx = lin >> 3;
  int bx = xcd * 16 + (idx & 15);   // gridDim.x == 128
  int by = idx >> 4;
  int m0 = bx * 128, n0 = by * 128;
  int wm = (wid >> 1) * 64, wn = (wid & 1) * 64;
  int r15 = lane & 15, g = lane >> 4;

  const unsigned short* aptr[4];
  int segoff[4];
  #pragma unroll
  for (int s = 0; s < 4; ++s) {
    int seg = wid * 4 + s;
    int slot = seg * 64 + lane;
    int m = slot >> 3, lc = (slot & 7) ^ (m & 7);
    aptr[s] = A + (size_t)(m0 + m) * K + lc * 8;
    segoff[s] = seg * 1024;
  }
  const unsigned short* bfbase = Bt + (size_t)((n0 + wn) >> 4) * 8192 + lane * 8;

  f32x4 acc[4][4] = {};
  s16x8 b[2][4][2];

  #pragma unroll
  for (int s = 0; s < 4; ++s) gl_lds16(aptr[s], (char*)a_lds[0] + segoff[s]);
  #pragma unroll
  for (int f = 0; f < 4; ++f)
    #pragma unroll
    for (int kk = 0; kk < 2; ++kk)
      b[0][f][kk] = *(const s16x8*)(bfbase + f * 8192 + kk * 512);

  #pragma unroll
  for (int it = 0; it < 8; ++it) {
    int cur = it & 1;
    if (it < 7) {
      int ksn = (it + 1) * 64;
      #pragma unroll
      for (int s = 0; s < 4; ++s)
        gl_lds16(aptr[s] + ksn, (char*)a_lds[cur ^ 1] + segoff[s]);
      asm volatile("s_waitcnt vmcnt(4)" ::: "memory");
    } else {
      asm volatile("s_waitcnt vmcnt(0)" ::: "memory");
    }
    __builtin_amdgcn_s_barrier();
    __builtin_amdgcn_sched_barrier(0);
    if (it < 7) {
      int kc0 = (it + 1) * 2;
      #pragma unroll
      for (int f = 0; f < 4; ++f)
        #pragma unroll
        for (int kk = 0; kk < 2; ++kk)
          b[cur ^ 1][f][kk] = *(const s16x8*)(bfbase + f * 8192 + (kc0 + kk) * 512);
    }
    const char* al = (const char*)a_lds[cur];
    #pragma unroll
    for (int kk = 0; kk < 2; ++kk) {
      s16x8 af[4];
      #pragma unroll
      for (int f = 0; f < 4; ++f) {
        int mm = wm + f * 16 + r15;
        af[f] = *(const s16x8*)(al + mm * 128 + (((kk * 4 + g) ^ (mm & 7)) * 16));
      }
      __builtin_amdgcn_s_setprio(1);
      #pragma unroll
      for (int fm = 0; fm < 4; ++fm)
        #pragma unroll
        for (int fn = 0; fn < 4; ++fn)
          acc[fm][fn] = mfma16(af[fm], b[cur][fn][kk], acc[fm][fn]);
      __builtin_amdgcn_s_setprio(0);
    }
    __builtin_amdgcn_s_barrier();
    __builtin_amdgcn_sched_barrier(0);
  }

  int g4 = g * 4;
  #pragma unroll
  for (int fm = 0; fm < 4; ++fm) {
    #pragma unroll
    for (int fn = 0; fn < 4; ++fn) {
      int col = n0 + wn + fn * 16 + r15;
      int row0 = m0 + wm + fm * 16 + g4;
      if (EPI == 3) {
        int blk = row0 >> 8, tok0 = row0 & 255;
        int sw = blk & 3, shI = (blk >> 2) & 3, stI = (blk >> 4) & 1, bI = blk >> 5;
        int tt = tok0 >> 6, hh = (tok0 >> 3) & 7, ww0 = tok0 & 7;
        size_t addr = (size_t)bI * 4194304 + (size_t)col * 8192
                    + (size_t)(stI * 4 + tt) * 1024 + (shI * 8 + hh) * 32 + sw * 8 + ww0;
        float4 o;
        float bb = bias[col];
        o.x = acc[fm][fn][0] + bb + bf2f(addbf[(size_t)(row0 + 0) * 512 + col]);
        o.y = acc[fm][fn][1] + bb + bf2f(addbf[(size_t)(row0 + 1) * 512 + col]);
        o.z = acc[fm][fn][2] + bb + bf2f(addbf[(size_t)(row0 + 2) * 512 + col]);
        o.w = acc[fm][fn][3] + bb + bf2f(addbf[(size_t)(row0 + 3) * 512 + col]);
        *(float4*)(Cf + addr) = o;
      } else {
        #pragma unroll
        for (int r = 0; r < 4; ++r) {
          int row = row0 + r;
          float v = acc[fm][fn][r];
          if (EPI == 1) {
            Cbf[(size_t)row * 512 + col] = f2bf(v + bf2f(addbf[(size_t)row * 512 + col]));
          } else if (EPI == 2) {
            Cbf[(size_t)row * 512 + col] = f2bf(fmaxf(v + bias[col], 0.f));
          }
        }
      }
    }
  }
}

// ---------- GEMM-256 (R8-proven math, register cap REMOVED): 256x128 tile, 8 waves ----------
// Swapped MFMA (b,a): lane r15 = token row, regs = 4 consecutive cols -> vector epilogue.
// Used for QKV (EPI=0) only. gridDim.x MUST be 64.
template<int EPI>
__global__ __launch_bounds__(512) void k_gemm256(
    const unsigned short* __restrict__ A, const unsigned short* __restrict__ Bt,
    int M, int N,
    unsigned short* __restrict__ Cbf,
    unsigned short* __restrict__ vTout)
{
  constexpr int K = 512;
  __shared__ __align__(16) unsigned short a_lds[2][256 * 64];   // 2 x 32KB
  int tid = threadIdx.x, lane = tid & 63, wid = tid >> 6;
  int lin = blockIdx.y * gridDim.x + blockIdx.x;
  int xcd = lin & 7, idx = lin >> 3;
  int bx = xcd * 8 + (idx & 7);     // gridDim.x == 64; per-XCD A-chunk = 2MB
  int by = idx >> 3;
  int m0 = bx * 256, n0 = by * 128;
  int wm = (wid >> 1) * 64, wn = (wid & 1) * 64;
  int r15 = lane & 15, g = lane >> 4;

  const unsigned short* aptr[4];
  int segoff[4];
  #pragma unroll
  for (int s = 0; s < 4; ++s) {
    int seg = wid * 4 + s;
    int slot = seg * 64 + lane;
    int m = slot >> 3, lc = (slot & 7) ^ (m & 7);
    aptr[s] = A + (size_t)(m0 + m) * K + lc * 8;
    segoff[s] = seg * 1024;
  }
  const unsigned short* bfbase = Bt + (size_t)((n0 + wn) >> 4) * 8192 + lane * 8;

  f32x4 acc[4][4] = {};
  s16x8 b[2][4][2];

  #pragma unroll
  for (int s = 0; s < 4; ++s) gl_lds16(aptr[s], (char*)a_lds[0] + segoff[s]);
  #pragma unroll
  for (int f = 0; f < 4; ++f)
    #pragma unroll
    for (int kk = 0; kk < 2; ++kk)
      b[0][f][kk] = *(const s16x8*)(bfbase + f * 8192 + kk * 512);

  #pragma unroll
  for (int it = 0; it < 8; ++it) {
    int cur = it & 1;
    if (it < 7) {
      int ksn = (it + 1) * 64;
      #pragma unroll
      for (int s = 0; s < 4; ++s)
        gl_lds16(aptr[s] + ksn, (char*)a_lds[cur ^ 1] + segoff[s]);
      asm volatile("s_waitcnt vmcnt(4)" ::: "memory");
    } else {
      asm volatile("s_waitcnt vmcnt(0)" ::: "memory");
    }
    __builtin_amdgcn_s_barrier();
    __builtin_amdgcn_sched_barrier(0);
    if (it < 7) {
      int kc0 = (it + 1) * 2;
      #pragma unroll
      for (int f = 0; f < 4; ++f)
        #pragma unroll
        for (int kk = 0; kk < 2; ++kk)
          b[cur ^ 1][f][kk] = *(const s16x8*)(bfbase + f * 8192 + (kc0 + kk) * 512);
    }
    const char* al = (const char*)a_lds[cur];
    #pragma unroll
    for (int kk = 0; kk < 2; ++kk) {
      s16x8 af[4];
      #pragma unroll
      for (int f = 0; f < 4; ++f) {
        int mm = wm + f * 16 + r15;
        af[f] = *(const s16x8*)(al + mm * 128 + (((kk * 4 + g) ^ (mm & 7)) * 16));
      }
      __builtin_amdgcn_s_setprio(1);
      #pragma unroll
      for (int fm = 0; fm < 4; ++fm)
        #pragma unroll
        for (int fn = 0; fn < 4; ++fn)
          acc[fm][fn] = mfma16(b[cur][fn][kk], af[fm], acc[fm][fn]);   // SWAPPED: regs=cols
      __builtin_amdgcn_s_setprio(0);
    }
    __builtin_amdgcn_s_barrier();
    __builtin_amdgcn_sched_barrier(0);
  }

  // epilogue: lane holds (row m, 4 consecutive cols) per tile -> vector stores
  #pragma unroll
  for (int fm = 0; fm < 4; ++fm) {
    int m = m0 + wm + fm * 16 + r15;
    #pragma unroll
    for (int fn = 0; fn < 4; ++fn) {
      int nc = n0 + wn + fn * 16 + g * 4;
      f32x4 v = acc[fm][fn];
      if (EPI == 0 && nc >= 1024) {
        int h = (nc - 1024) >> 6, e0 = nc & 63;
        int blk = m >> 8, tok = m & 255;
        size_t vb = (((size_t)blk * 8 + h) * 64 + e0) * 256 + tok;
        #pragma unroll
        for (int r = 0; r < 4; ++r) vTout[vb + (size_t)r * 256] = f2bf(v[r]);
      } else {
        *(uint2*)(Cbf + (size_t)m * 1536 + nc) =
            make_uint2(cvt_pk_bf16(v[0], v[1]), cvt_pk_bf16(v[2], v[3]));
      }
    }
  }
}

// ---------- K3: block-local attention, counted-vmcnt double-buffered staging ----------
__global__ __launch_bounds__(256, 1) void k_attn(
    const unsigned short* __restrict__ qkv, const unsigned short* __restrict__ vT,
    const float* __restrict__ dtb, const float* __restrict__ dhb, const float* __restrict__ dwb,
    unsigned short* __restrict__ aout)
{
  __shared__ __align__(16) unsigned short k_lds[2][64 * 64];
  __shared__ __align__(16) unsigned short v_lds[2][64 * 64];
  __shared__ __align__(16) unsigned short p_lds[4][64 * 64];
  __shared__ float bt_s[8], bh_s[16], bw_s[16];

  const float L2E = 1.44269504f;
  const float SC = 0.125f * 1.44269504f;   // 1/sqrt(64) * log2(e)

  int tid = threadIdx.x, lane = tid & 63, wid = tid >> 6;
  int bk = blockIdx.x >> 3, h = blockIdx.x & 7;
  if (tid < 7) bt_s[tid] = dtb[h * 7 + tid] * L2E;
  else if (tid < 22) bh_s[tid - 7] = dhb[h * 15 + tid - 7] * L2E;
  else if (tid < 37) bw_s[tid - 22] = dwb[h * 15 + tid - 22] * L2E;

  int r15 = lane & 15, g = lane >> 4;
  int wq0 = wid * 64;
  size_t bkBase = (size_t)bk * 256;
  const unsigned short* kbase = qkv + 512 + h * 64;
  const unsigned short* vbase = vT + ((size_t)bk * 8 + h) * 64 * 256;

  s16x8 qf[4][2];
  #pragma unroll
  for (int fn = 0; fn < 4; ++fn)
    #pragma unroll
    for (int kk = 0; kk < 2; ++kk)
      qf[fn][kk] = *(const s16x8*)(qkv + (bkBase + wq0 + fn * 16 + r15) * 1536
                                   + h * 64 + kk * 32 + g * 8);

  float btoff[4], hb[7], wb[4];

  #pragma unroll
  for (int s = 0; s < 4; ++s) {
    int sg = wid * 4 + s;
    if (sg < 8) {
      int slot = sg * 64 + lane;
      int m = slot >> 3, lc = (slot & 7) ^ (m & 7);
      gl_lds16(kbase + (bkBase + m) * 1536 + lc * 8, (char*)(&k_lds[0][0]) + sg * 1024);
    } else {
      int sg2 = sg - 8;
      int slot = sg2 * 64 + lane;
      int e = slot >> 3, lc = (slot & 7) ^ (e & 7);
      gl_lds16(vbase + (size_t)e * 256 + lc * 8, (char*)(&v_lds[0][0]) + sg2 * 1024);
    }
  }
  __syncthreads();

  {
    int Dh = (r15 >> 3) - (g >> 1) + 7;
    int Wb = (r15 & 7) - 4 * (g & 1) + 7;
    #pragma unroll
    for (int mt = 0; mt < 4; ++mt) btoff[mt] = bt_s[wid + 3 - mt];
    #pragma unroll
    for (int d = 0; d < 7; ++d) hb[d] = bh_s[Dh + 2 * d - 6];
    #pragma unroll
    for (int r = 0; r < 4; ++r) wb[r] = bw_s[Wb - r];
  }

  f32x4 o[4][4] = {};
  float mrun[4] = {-1e30f, -1e30f, -1e30f, -1e30f};
  float lrun[4] = {0.f, 0.f, 0.f, 0.f};
  char* p_w = (char*)(&p_lds[wid][0]);

  #pragma unroll
  for (int mt = 0; mt < 4; ++mt) {
    int cur = mt & 1;
    if (mt < 3) {
      int m0n = (mt + 1) * 64;
      #pragma unroll
      for (int s = 0; s < 4; ++s) {
        int sg = wid * 4 + s;
        if (sg < 8) {
          int slot = sg * 64 + lane;
          int m = slot >> 3, lc = (slot & 7) ^ (m & 7);
          gl_lds16(kbase + (bkBase + m0n + m) * 1536 + lc * 8,
                   (char*)(&k_lds[cur ^ 1][0]) + sg * 1024);
        } else {
          int sg2 = sg - 8;
          int slot = sg2 * 64 + lane;
          int e = slot >> 3, lc = (slot & 7) ^ (e & 7);
          gl_lds16(vbase + (size_t)e * 256 + m0n + lc * 8,
                   (char*)(&v_lds[cur ^ 1][0]) + sg2 * 1024);
        }
      }
    }
    if (mt > 0) {
      if (mt < 3) asm volatile("s_waitcnt vmcnt(4)" ::: "memory");
      else        asm volatile("s_waitcnt vmcnt(0)" ::: "memory");
      __builtin_amdgcn_s_barrier();
      __builtin_amdgcn_sched_barrier(0);
    }
    const char* kl = (const char*)(&k_lds[cur][0]);
    const char* vl = (const char*)(&v_lds[cur][0]);

    f32x4 st[4][4] = {};
    #pragma unroll
    for (int kk = 0; kk < 2; ++kk) {
      s16x8 kf[4];
      #pragma unroll
      for (int fm = 0; fm < 4; ++fm) {
        int m = fm * 16 + r15;
        kf[fm] = *(const s16x8*)(kl + m * 128 + (((kk * 4 + g) ^ (m & 7)) * 16));
      }
      __builtin_amdgcn_s_setprio(1);
      #pragma unroll
      for (int fm = 0; fm < 4; ++fm)
        #pragma unroll
        for (int fn = 0; fn < 4; ++fn)
          st[fm][fn] = mfma16(kf[fm], qf[fn][kk], st[fm][fn]);
      __builtin_amdgcn_s_setprio(0);
    }

    #pragma unroll
    for (int fn = 0; fn < 4; ++fn) {
      float vals[16];
      float mx = -1e30f;
      #pragma unroll
      for (int fm = 0; fm < 4; ++fm) {
        float cc = btoff[mt] + hb[fn - fm + 3];
        #pragma unroll
        for (int r = 0; r < 4; ++r) {
          float v = fmaf(st[fm][fn][r], SC, cc) + wb[r];
          vals[fm * 4 + r] = v;
          mx = fmaxf(mx, v);
        }
      }
      mx = fmaxf(mx, __shfl_xor(mx, 16));
      mx = fmaxf(mx, __shfl_xor(mx, 32));
      if (!__all(mx <= mrun[fn] + 8.f)) {       // T13 defer-rescale
        float mnew = fmaxf(mrun[fn], mx);
        float al = EXP2F(mrun[fn] - mnew);
        mrun[fn] = mnew;
        lrun[fn] *= al;
        #pragma unroll
        for (int fe = 0; fe < 4; ++fe)
          #pragma unroll
          for (int r = 0; r < 4; ++r)
            o[fe][fn][r] *= al;
      }
      float m_c = mrun[fn];
      float p[16]; float sum = 0.f;
      #pragma unroll
      for (int i = 0; i < 16; ++i) { p[i] = EXP2F(vals[i] - m_c); sum += p[i]; }
      sum += __shfl_xor(sum, 16);
      sum += __shfl_xor(sum, 32);
      lrun[fn] += sum;
      int nl = fn * 16 + r15;
      char* prow = p_w + nl * 128 + (g & 1) * 8;
      #pragma unroll
      for (int fm = 0; fm < 4; ++fm) {
        unsigned u0 = cvt_pk_bf16(p[fm * 4 + 0], p[fm * 4 + 1]);
        unsigned u1 = cvt_pk_bf16(p[fm * 4 + 2], p[fm * 4 + 3]);
        int lc = fm * 2 + (g >> 1);
        *(uint2*)(prow + ((lc ^ (nl & 7)) * 16)) = make_uint2(u0, u1);
      }
    }
    asm volatile("s_waitcnt lgkmcnt(0)" ::: "memory");
    __builtin_amdgcn_sched_barrier(0);

    #pragma unroll
    for (int mm = 0; mm < 2; ++mm) {
      s16x8 vf[4], pf[4];
      #pragma unroll
      for (int fe = 0; fe < 4; ++fe) {
        int e = fe * 16 + r15;
        vf[fe] = *(const s16x8*)(vl + e * 128 + (((mm * 4 + g) ^ (e & 7)) * 16));
      }
      #pragma unroll
      for (int fn = 0; fn < 4; ++fn) {
        int nl = fn * 16 + r15;
        pf[fn] = *(const s16x8*)(p_w + nl * 128 + (((mm * 4 + g) ^ (nl & 7)) * 16));
      }
      __builtin_amdgcn_s_setprio(1);
      #pragma unroll
      for (int fe = 0; fe < 4; ++fe)
        #pragma unroll
        for (int fn = 0; fn < 4; ++fn)
          o[fe][fn] = mfma16(vf[fe], pf[fn], o[fe][fn]);
      __builtin_amdgcn_s_setprio(0);
    }
    __builtin_amdgcn_s_barrier();
    __builtin_amdgcn_sched_barrier(0);
  }

  #pragma unroll
  for (int fn = 0; fn < 4; ++fn) {
    float inv = 1.f / lrun[fn];
    size_t rowb = (bkBase + wq0 + fn * 16 + r15) * 512 + h * 64;
    #pragma unroll
    for (int fe = 0; fe < 4; ++fe) {
      unsigned u0 = cvt_pk_bf16(o[fe][fn][0] * inv, o[fe][fn][1] * inv);
      unsigned u1 = cvt_pk_bf16(o[fe][fn][2] * inv, o[fe][fn][3] * inv);
      *(uint2*)(aout + rowb + fe * 16 + g * 4) = make_uint2(u0, u1);
    }
  }
}

// ---------- K5: LN2 (rowwise over 512), bf16 in -> bf16 out ----------
__global__ __launch_bounds__(256) void k_ln2(
    const unsigned short* __restrict__ in, const float* __restrict__ g2, const float* __restrict__ b2,
    unsigned short* __restrict__ out)
{
  int token = blockIdx.x * 4 + (threadIdx.x >> 6);
  int lane = threadIdx.x & 63;
  s16x8 v8 = *(const s16x8*)(in + (size_t)token * 512 + lane * 8);
  float vv[8]; float s = 0.f, ss = 0.f;
  #pragma unroll
  for (int i = 0; i < 8; ++i) {
    float v = bf2f((unsigned short)v8[i]); vv[i] = v; s += v; ss += v * v;
  }
  #pragma unroll
  for (int d = 1; d < 64; d <<= 1) { s += __shfl_xor(s, d); ss += __shfl_xor(ss, d); }
  float mean = s * (1.f / 512.f);
  float var = ss * (1.f / 512.f) - mean * mean;
  float rs = rsqrtf(var + 1e-5f);
  const float4 gA = *(const float4*)(g2 + lane * 8);
  const float4 gB = *(const float4*)(g2 + lane * 8 + 4);
  const float4 bA = *(const float4*)(b2 + lane * 8);
  const float4 bB = *(const float4*)(b2 + lane * 8 + 4);
  float gv[8] = {gA.x, gA.y, gA.z, gA.w, gB.x, gB.y, gB.z, gB.w};
  float bv[8] = {bA.x, bA.y, bA.z, bA.w, bB.x, bB.y, bB.z, bB.w};
  s16x8 o8;
  #pragma unroll
  for (int i = 0; i < 8; ++i)
    o8[i] = (short)f2bf((vv[i] - mean) * rs * gv[i] + bv[i]);
  *(s16x8*)(out + (size_t)token * 512 + lane * 8) = o8;
}

// ---------- host ----------
extern "C" void kernel_launch(void* const* d_in, const int* in_sizes, int n_in,
                              void* d_out, int out_size, void* d_ws, size_t ws_size,
                              hipStream_t stream)
{
  const float* x   = (const float*)d_in[0];
  const float* dtb = (const float*)d_in[1];
  const float* dhb = (const float*)d_in[2];
  const float* dwb = (const float*)d_in[3];
  const float* g1  = (const float*)d_in[4];
  const float* bb1 = (const float*)d_in[5];
  const float* wq  = (const float*)d_in[6];
  const float* wk  = (const float*)d_in[7];
  const float* wv  = (const float*)d_in[8];
  const float* wp  = (const float*)d_in[9];
  const float* g2  = (const float*)d_in[10];
  const float* bb2 = (const float*)d_in[11];
  const float* w1  = (const float*)d_in[12];
  const float* fb1 = (const float*)d_in[13];
  const float* w2  = (const float*)d_in[14];
  const float* fb2 = (const float*)d_in[15];

  char* ws = (char*)d_ws;
  unsigned short* xb   = (unsigned short*)(ws + 0);          // resid bf16 [K1..gemm1]
  unsigned short* vT   = (unsigned short*)(ws + 33554432);   // v^T bf16 [gemm0..attn]
  unsigned short* out1b= (unsigned short*)(ws + 33554432);   // proj+resid bf16 [gemm1..gemm3]
  unsigned short* qkv  = (unsigned short*)(ws + 67108864);   // q,k bf16 [gemm0..attn]; h1 [gemm2..gemm3]
  unsigned short* xn   = (unsigned short*)(ws + 117440512);  // xn; attn_out; y
  unsigned short* qkvT = (unsigned short*)(ws + 134217728);
  unsigned short* wpT  = (unsigned short*)(ws + 135790592);
  unsigned short* w1T  = (unsigned short*)(ws + 136314880);
  unsigned short* w2T  = (unsigned short*)(ws + 136839168);

  unsigned short* attn_out = xn;
  unsigned short* yb = xn;
  unsigned short* h1 = qkv;
  float* outp = (float*)d_out;

  k_gather_ln<<<1024 + 6144, 256, 0, stream>>>(x, g1, bb1, xb, xn,
      wq, wk, wv, wp, w1, w2, qkvT, wpT, w1T, w2T);
  k_gemm256<0><<<dim3(64, 12), 512, 0, stream>>>(xn, qkvT, 16384, 1536, qkv, vT);
  k_attn<<<512, 256, 0, stream>>>(qkv, vT, dtb, dhb, dwb, attn_out);
  k_gemm<1><<<dim3(128, 4), 256, 0, stream>>>(attn_out, wpT, 16384, 512, out1b, nullptr, nullptr, xb, nullptr);
  k_ln2<<<4096, 256, 0, stream>>>(out1b, g2, bb2, yb);
  k_gemm<2><<<dim3(128, 4), 256, 0, stream>>>(yb, w1T, 16384, 512, h1, nullptr, fb1, nullptr, nullptr);
  k_gemm<3><<<dim3(128, 4), 256, 0, stream>>>(h1, w2T, 16384, 512, nullptr, outp, fb2, out1b, nullptr);
}

// Round 12
// 150.384 us; speedup vs baseline: 1.0824x; 1.0436x over previous
//
#include <hip/hip_runtime.h>
#include <hip/hip_bf16.h>
#include <stdint.h>

// ---------- types & helpers ----------
typedef __attribute__((ext_vector_type(4))) float f32x4;
typedef __attribute__((ext_vector_type(8))) short s16x8;
typedef __attribute__((ext_vector_type(4))) short s16x4;
typedef __attribute__((ext_vector_type(8))) __bf16 b16x8;

__device__ __forceinline__ f32x4 mfma16(s16x8 a, s16x8 b, f32x4 c) {
  return __builtin_amdgcn_mfma_f32_16x16x32_bf16(
      __builtin_bit_cast(b16x8, a), __builtin_bit_cast(b16x8, b), c, 0, 0, 0);
}

__device__ __forceinline__ void gl_lds16(const void* g, void* l) {
  __builtin_amdgcn_global_load_lds(
      (const __attribute__((address_space(1))) void*)g,
      (__attribute__((address_space(3))) void*)l, 16, 0, 0);
}

__device__ __forceinline__ unsigned short f2bf(float f) {
  union { float f; unsigned u; } v; v.f = f;
  unsigned u = v.u;
  return (unsigned short)((u + 0x7FFFu + ((u >> 16) & 1u)) >> 16);
}

__device__ __forceinline__ float bf2f(unsigned short u) {
  union { unsigned u; float f; } v; v.u = ((unsigned)u) << 16; return v.f;
}

__device__ __forceinline__ unsigned cvt_pk_bf16(float a, float b) {
  unsigned r;
  asm("v_cvt_pk_bf16_f32 %0, %1, %2" : "=v"(r) : "v"(a), "v"(b));
  return r;
}

#if __has_builtin(__builtin_amdgcn_exp2f)
#define EXP2F(x) __builtin_amdgcn_exp2f(x)
#else
#define EXP2F(x) exp2f(x)
#endif

// B pre-fragment offset: n_f=n>>4, r=n&15, kc=k>>5, g=(k>>3)&3, j=k&7
__device__ __forceinline__ int bfrag_off(int n, int k) {
  return ((((n >> 4) * 16 + (k >> 5)) * 4 + ((k >> 3) & 3)) * 16 + (n & 15)) * 8 + (k & 7);
}

// ---------- K1: gather x -> blocked layout + LN1; blocks >=1024 do weight prep ----------
__global__ __launch_bounds__(256) void k_gather_ln(
    const float* __restrict__ x, const float* __restrict__ g1, const float* __restrict__ b1,
    unsigned short* __restrict__ xb, unsigned short* __restrict__ xn,
    const float* __restrict__ wq, const float* __restrict__ wk, const float* __restrict__ wv,
    const float* __restrict__ wp, const float* __restrict__ w1, const float* __restrict__ w2,
    unsigned short* __restrict__ qkvT, unsigned short* __restrict__ wpT,
    unsigned short* __restrict__ w1T, unsigned short* __restrict__ w2T)
{
  if (blockIdx.x >= 1024) {            // ---- weight prep path (pre-fragmented B) ----
    int i = (blockIdx.x - 1024) * 256 + threadIdx.x;
    if (i < 786432) {
      int n = i >> 9, d = i & 511;
      const float* src = (n < 512) ? wq : (n < 1024 ? wk : wv);
      int nn = n & 511;
      int h = nn >> 6, e = nn & 63;
      qkvT[bfrag_off(n, d)] = f2bf(src[((size_t)h * 512 + d) * 64 + e]);
    } else {
      int j = i - 786432;
      int w = j >> 18;
      int o = j & 262143;
      const float* s = (w == 0) ? wp : (w == 1 ? w1 : w2);
      unsigned short* dst = (w == 0) ? wpT : (w == 1 ? w1T : w2T);
      dst[bfrag_off(o >> 9, o & 511)] = f2bf(s[o]);
    }
    return;
  }
  __shared__ float lx[16][517];
  int gid = blockIdx.x;
  int h2 = gid & 1, hh = (gid >> 1) & 7, tt = (gid >> 4) & 3,
      shI = (gid >> 6) & 3, stI = (gid >> 8) & 1, bI = (gid >> 9) & 1;
  const float* xbase = x + (size_t)bI * 4194304 + (size_t)(stI * 4 + tt) * 1024
                       + (shI * 8 + hh) * 32 + h2 * 16;
  int t = threadIdx.x;
  for (int i = 0; i < 8; ++i) {
    int slot = i * 256 + t;
    int c = slot >> 2, w8 = slot & 3;
    const float4 v = *(const float4*)(xbase + (size_t)c * 8192 + w8 * 4);
    lx[w8 * 4 + 0][c] = v.x; lx[w8 * 4 + 1][c] = v.y;
    lx[w8 * 4 + 2][c] = v.z; lx[w8 * 4 + 3][c] = v.w;
  }
  __syncthreads();
  int lane = t & 63, wid = t >> 6;
  for (int q = 0; q < 4; ++q) {
    int widx = wid * 4 + q;
    float vv[8]; float s = 0.f, ss = 0.f;
    #pragma unroll
    for (int i = 0; i < 8; ++i) { float v = lx[widx][lane + i * 64]; vv[i] = v; s += v; ss += v * v; }
    #pragma unroll
    for (int d = 1; d < 64; d <<= 1) { s += __shfl_xor(s, d); ss += __shfl_xor(ss, d); }
    float mean = s * (1.f / 512.f);
    float var = ss * (1.f / 512.f) - mean * mean;
    float rs = rsqrtf(var + 1e-5f);
    int sw = h2 * 2 + (widx >> 3), ww = widx & 7;
    int blk = ((bI * 2 + stI) * 4 + shI) * 4 + sw;
    int n = tt * 64 + hh * 8 + ww;
    size_t base = ((size_t)blk * 256 + n) * 512;
    #pragma unroll
    for (int i = 0; i < 8; ++i) {
      int c = lane + i * 64;
      float v = vv[i];
      xb[base + c] = f2bf(v);
      xn[base + c] = f2bf((v - mean) * rs * g1[c] + b1[c]);
    }
  }
}

// ---------- GEMM (R7/R9-proven): 128x128 tile, A via LDS dbuf, B pre-frag via L2->regs ----------
// Counted vmcnt(4): queue at wait = [A(it)4, B(it)8 | A(it+1)4]. gridDim.x MUST be 128.
// EPI: 0 = QKV (bf16, V redirected transposed)  1 = proj (+bf16 resid -> bf16)
//      2 = FFN1 (+bias, relu, bf16)             3 = FFN2 (+bias +bf16 addf, f32 DIRECT to
//          (B,C,T,H,W) output layout -- scatter fused, float4 stores)
template<int EPI>
__global__ __launch_bounds__(256, 2) void k_gemm(
    const unsigned short* __restrict__ A, const unsigned short* __restrict__ Bt,
    int M, int N,
    unsigned short* __restrict__ Cbf, float* __restrict__ Cf,
    const float* __restrict__ bias,
    const unsigned short* __restrict__ addbf,
    unsigned short* __restrict__ vTout)
{
  constexpr int K = 512;
  __shared__ __align__(16) unsigned short a_lds[2][128 * 64];
  int tid = threadIdx.x, lane = tid & 63, wid = tid >> 6;
  int lin = blockIdx.y * gridDim.x + blockIdx.x;
  int xcd = lin & 7, idx = lin >> 3;
  int bx = xcd * 16 + (idx & 15);   // gridDim.x == 128
  int by = idx >> 4;
  int m0 = bx * 128, n0 = by * 128;
  int wm = (wid >> 1) * 64, wn = (wid & 1) * 64;
  int r15 = lane & 15, g = lane >> 4;

  // A staging addresses (16 segs of 1KB; 4 per wave)
  const unsigned short* aptr[4];
  int segoff[4];
  #pragma unroll
  for (int s = 0; s < 4; ++s) {
    int seg = wid * 4 + s;
    int slot = seg * 64 + lane;
    int m = slot >> 3, lc = (slot & 7) ^ (m & 7);
    aptr[s] = A + (size_t)(m0 + m) * K + lc * 8;
    segoff[s] = seg * 1024;
  }
  // B fragment base: frag(fn, kc) at bfbase + fn*8192 + kc*512 (1KB contiguous/wave)
  const unsigned short* bfbase = Bt + (size_t)((n0 + wn) >> 4) * 8192 + lane * 8;

  f32x4 acc[4][4] = {};
  s16x8 b[2][4][2];   // [iter parity][fn][kk] -- static after full unroll

  // prologue: stage A(0), load B(0)
  #pragma unroll
  for (int s = 0; s < 4; ++s) gl_lds16(aptr[s], (char*)a_lds[0] + segoff[s]);
  #pragma unroll
  for (int f = 0; f < 4; ++f)
    #pragma unroll
    for (int kk = 0; kk < 2; ++kk)
      b[0][f][kk] = *(const s16x8*)(bfbase + f * 8192 + kk * 512);

  #pragma unroll
  for (int it = 0; it < 8; ++it) {
    int cur = it & 1;
    if (it < 7) {
      int ksn = (it + 1) * 64;
      #pragma unroll
      for (int s = 0; s < 4; ++s)
        gl_lds16(aptr[s] + ksn, (char*)a_lds[cur ^ 1] + segoff[s]);
      asm volatile("s_waitcnt vmcnt(4)" ::: "memory");   // A(it)+B(it) retired
    } else {
      asm volatile("s_waitcnt vmcnt(0)" ::: "memory");
    }
    __builtin_amdgcn_s_barrier();
    __builtin_amdgcn_sched_barrier(0);
    if (it < 7) {                      // B(it+1) -> regs, hidden under MFMA
      int kc0 = (it + 1) * 2;
      #pragma unroll
      for (int f = 0; f < 4; ++f)
        #pragma unroll
        for (int kk = 0; kk < 2; ++kk)
          b[cur ^ 1][f][kk] = *(const s16x8*)(bfbase + f * 8192 + (kc0 + kk) * 512);
    }
    const char* al = (const char*)a_lds[cur];
    #pragma unroll
    for (int kk = 0; kk < 2; ++kk) {
      s16x8 af[4];
      #pragma unroll
      for (int f = 0; f < 4; ++f) {
        int mm = wm + f * 16 + r15;
        af[f] = *(const s16x8*)(al + mm * 128 + (((kk * 4 + g) ^ (mm & 7)) * 16));
      }
      __builtin_amdgcn_s_setprio(1);
      #pragma unroll
      for (int fm = 0; fm < 4; ++fm)
        #pragma unroll
        for (int fn = 0; fn < 4; ++fn)
          acc[fm][fn] = mfma16(af[fm], b[cur][fn][kk], acc[fm][fn]);
      __builtin_amdgcn_s_setprio(0);
    }
    __builtin_amdgcn_s_barrier();      // a_lds[cur] consumed -> reusable next iter
    __builtin_amdgcn_sched_barrier(0);
  }

  int g4 = g * 4;
  #pragma unroll
  for (int fm = 0; fm < 4; ++fm) {
    #pragma unroll
    for (int fn = 0; fn < 4; ++fn) {
      int col = n0 + wn + fn * 16 + r15;
      int row0 = m0 + wm + fm * 16 + g4;
      if (EPI == 0 && col >= 1024) {
        int h = (col - 1024) >> 6, e = col & 63;
        int blk = row0 >> 8, mtok = row0 & 255;
        s16x4 pk;
        #pragma unroll
        for (int r = 0; r < 4; ++r) pk[r] = (short)f2bf(acc[fm][fn][r]);
        *(s16x4*)(vTout + (((size_t)blk * 8 + h) * 64 + e) * 256 + mtok) = pk;
      } else if (EPI == 3) {
        // fused scatter: rows row0..row0+3 are 4 consecutive ww (row0%8 in {0,4})
        int blk = row0 >> 8, tok0 = row0 & 255;
        int sw = blk & 3, shI = (blk >> 2) & 3, stI = (blk >> 4) & 1, bI = blk >> 5;
        int tt = tok0 >> 6, hh = (tok0 >> 3) & 7, ww0 = tok0 & 7;
        size_t addr = (size_t)bI * 4194304 + (size_t)col * 8192
                    + (size_t)(stI * 4 + tt) * 1024 + (shI * 8 + hh) * 32 + sw * 8 + ww0;
        float4 o;
        float bb = bias[col];
        o.x = acc[fm][fn][0] + bb + bf2f(addbf[(size_t)(row0 + 0) * 512 + col]);
        o.y = acc[fm][fn][1] + bb + bf2f(addbf[(size_t)(row0 + 1) * 512 + col]);
        o.z = acc[fm][fn][2] + bb + bf2f(addbf[(size_t)(row0 + 2) * 512 + col]);
        o.w = acc[fm][fn][3] + bb + bf2f(addbf[(size_t)(row0 + 3) * 512 + col]);
        *(float4*)(Cf + addr) = o;
      } else {
        #pragma unroll
        for (int r = 0; r < 4; ++r) {
          int row = row0 + r;
          float v = acc[fm][fn][r];
          if (EPI == 0) {
            Cbf[(size_t)row * 1536 + col] = f2bf(v);
          } else if (EPI == 1) {
            Cbf[(size_t)row * 512 + col] = f2bf(v + bf2f(addbf[(size_t)row * 512 + col]));
          } else if (EPI == 2) {
            Cbf[(size_t)row * 512 + col] = f2bf(fmaxf(v + bias[col], 0.f));
          }
        }
      }
    }
  }
}

// ---------- K3: block-local attention, counted-vmcnt double-buffered staging ----------
__global__ __launch_bounds__(256, 1) void k_attn(
    const unsigned short* __restrict__ qkv, const unsigned short* __restrict__ vT,
    const float* __restrict__ dtb, const float* __restrict__ dhb, const float* __restrict__ dwb,
    unsigned short* __restrict__ aout)
{
  __shared__ __align__(16) unsigned short k_lds[2][64 * 64];
  __shared__ __align__(16) unsigned short v_lds[2][64 * 64];
  __shared__ __align__(16) unsigned short p_lds[4][64 * 64];
  __shared__ float bt_s[8], bh_s[16], bw_s[16];

  const float L2E = 1.44269504f;
  const float SC = 0.125f * 1.44269504f;   // 1/sqrt(64) * log2(e)

  int tid = threadIdx.x, lane = tid & 63, wid = tid >> 6;
  int bk = blockIdx.x >> 3, h = blockIdx.x & 7;
  if (tid < 7) bt_s[tid] = dtb[h * 7 + tid] * L2E;
  else if (tid < 22) bh_s[tid - 7] = dhb[h * 15 + tid - 7] * L2E;
  else if (tid < 37) bw_s[tid - 22] = dwb[h * 15 + tid - 22] * L2E;

  int r15 = lane & 15, g = lane >> 4;
  int wq0 = wid * 64;
  size_t bkBase = (size_t)bk * 256;
  const unsigned short* kbase = qkv + 512 + h * 64;
  const unsigned short* vbase = vT + ((size_t)bk * 8 + h) * 64 * 256;

  // Q fragments, resident (B-operand: lane r15 = q-row, g = k-octet)
  s16x8 qf[4][2];
  #pragma unroll
  for (int fn = 0; fn < 4; ++fn)
    #pragma unroll
    for (int kk = 0; kk < 2; ++kk)
      qf[fn][kk] = *(const s16x8*)(qkv + (bkBase + wq0 + fn * 16 + r15) * 1536
                                   + h * 64 + kk * 32 + g * 8);

  float btoff[4], hb[7], wb[4];

  // ---- stage mt=0 into buffer 0, then full-drain barrier (covers bias tables too) ----
  #pragma unroll
  for (int s = 0; s < 4; ++s) {
    int sg = wid * 4 + s;
    if (sg < 8) {
      int slot = sg * 64 + lane;
      int m = slot >> 3, lc = (slot & 7) ^ (m & 7);
      gl_lds16(kbase + (bkBase + m) * 1536 + lc * 8, (char*)(&k_lds[0][0]) + sg * 1024);
    } else {
      int sg2 = sg - 8;
      int slot = sg2 * 64 + lane;
      int e = slot >> 3, lc = (slot & 7) ^ (e & 7);
      gl_lds16(vbase + (size_t)e * 256 + lc * 8, (char*)(&v_lds[0][0]) + sg2 * 1024);
    }
  }
  __syncthreads();

  {
    int Dh = (r15 >> 3) - (g >> 1) + 7;
    int Wb = (r15 & 7) - 4 * (g & 1) + 7;
    #pragma unroll
    for (int mt = 0; mt < 4; ++mt) btoff[mt] = bt_s[wid + 3 - mt];
    #pragma unroll
    for (int d = 0; d < 7; ++d) hb[d] = bh_s[Dh + 2 * d - 6];
    #pragma unroll
    for (int r = 0; r < 4; ++r) wb[r] = bw_s[Wb - r];
  }

  f32x4 o[4][4] = {};                       // o[fe][fn] : O^T[e][n]
  float mrun[4] = {-1e30f, -1e30f, -1e30f, -1e30f};
  float lrun[4] = {0.f, 0.f, 0.f, 0.f};
  char* p_w = (char*)(&p_lds[wid][0]);

  #pragma unroll
  for (int mt = 0; mt < 4; ++mt) {
    int cur = mt & 1;
    if (mt < 3) {
      int m0n = (mt + 1) * 64;
      #pragma unroll
      for (int s = 0; s < 4; ++s) {
        int sg = wid * 4 + s;
        if (sg < 8) {
          int slot = sg * 64 + lane;
          int m = slot >> 3, lc = (slot & 7) ^ (m & 7);
          gl_lds16(kbase + (bkBase + m0n + m) * 1536 + lc * 8,
                   (char*)(&k_lds[cur ^ 1][0]) + sg * 1024);
        } else {
          int sg2 = sg - 8;
          int slot = sg2 * 64 + lane;
          int e = slot >> 3, lc = (slot & 7) ^ (e & 7);
          gl_lds16(vbase + (size_t)e * 256 + m0n + lc * 8,
                   (char*)(&v_lds[cur ^ 1][0]) + sg2 * 1024);
        }
      }
    }
    if (mt > 0) {
      if (mt < 3) asm volatile("s_waitcnt vmcnt(4)" ::: "memory");
      else        asm volatile("s_waitcnt vmcnt(0)" ::: "memory");
      __builtin_amdgcn_s_barrier();
      __builtin_amdgcn_sched_barrier(0);
    }
    const char* kl = (const char*)(&k_lds[cur][0]);
    const char* vl = (const char*)(&v_lds[cur][0]);

    // S^T[m][n] = sum_e K[m][e] Q[n][e]
    f32x4 st[4][4] = {};
    #pragma unroll
    for (int kk = 0; kk < 2; ++kk) {
      s16x8 kf[4];
      #pragma unroll
      for (int fm = 0; fm < 4; ++fm) {
        int m = fm * 16 + r15;
        kf[fm] = *(const s16x8*)(kl + m * 128 + (((kk * 4 + g) ^ (m & 7)) * 16));
      }
      __builtin_amdgcn_s_setprio(1);
      #pragma unroll
      for (int fm = 0; fm < 4; ++fm)
        #pragma unroll
        for (int fn = 0; fn < 4; ++fn)
          st[fm][fn] = mfma16(kf[fm], qf[fn][kk], st[fm][fn]);
      __builtin_amdgcn_s_setprio(0);
    }

    // online softmax in exp2 domain
    #pragma unroll
    for (int fn = 0; fn < 4; ++fn) {
      float vals[16];
      float mx = -1e30f;
      #pragma unroll
      for (int fm = 0; fm < 4; ++fm) {
        float cc = btoff[mt] + hb[fn - fm + 3];
        #pragma unroll
        for (int r = 0; r < 4; ++r) {
          float v = fmaf(st[fm][fn][r], SC, cc) + wb[r];
          vals[fm * 4 + r] = v;
          mx = fmaxf(mx, v);
        }
      }
      mx = fmaxf(mx, __shfl_xor(mx, 16));
      mx = fmaxf(mx, __shfl_xor(mx, 32));
      if (!__all(mx <= mrun[fn] + 8.f)) {       // T13 defer-rescale
        float mnew = fmaxf(mrun[fn], mx);
        float al = EXP2F(mrun[fn] - mnew);
        mrun[fn] = mnew;
        lrun[fn] *= al;
        #pragma unroll
        for (int fe = 0; fe < 4; ++fe)
          #pragma unroll
          for (int r = 0; r < 4; ++r)
            o[fe][fn][r] *= al;
      }
      float m_c = mrun[fn];
      float p[16]; float sum = 0.f;
      #pragma unroll
      for (int i = 0; i < 16; ++i) { p[i] = EXP2F(vals[i] - m_c); sum += p[i]; }
      sum += __shfl_xor(sum, 16);
      sum += __shfl_xor(sum, 32);
      lrun[fn] += sum;
      int nl = fn * 16 + r15;
      char* prow = p_w + nl * 128 + (g & 1) * 8;
      #pragma unroll
      for (int fm = 0; fm < 4; ++fm) {
        unsigned u0 = cvt_pk_bf16(p[fm * 4 + 0], p[fm * 4 + 1]);
        unsigned u1 = cvt_pk_bf16(p[fm * 4 + 2], p[fm * 4 + 3]);
        int lc = fm * 2 + (g >> 1);
        *(uint2*)(prow + ((lc ^ (nl & 7)) * 16)) = make_uint2(u0, u1);
      }
    }
    asm volatile("s_waitcnt lgkmcnt(0)" ::: "memory");
    __builtin_amdgcn_sched_barrier(0);

    // O^T += V^T * P^T
    #pragma unroll
    for (int mm = 0; mm < 2; ++mm) {
      s16x8 vf[4], pf[4];
      #pragma unroll
      for (int fe = 0; fe < 4; ++fe) {
        int e = fe * 16 + r15;
        vf[fe] = *(const s16x8*)(vl + e * 128 + (((mm * 4 + g) ^ (e & 7)) * 16));
      }
      #pragma unroll
      for (int fn = 0; fn < 4; ++fn) {
        int nl = fn * 16 + r15;
        pf[fn] = *(const s16x8*)(p_w + nl * 128 + (((mm * 4 + g) ^ (nl & 7)) * 16));
      }
      __builtin_amdgcn_s_setprio(1);
      #pragma unroll
      for (int fe = 0; fe < 4; ++fe)
        #pragma unroll
        for (int fn = 0; fn < 4; ++fn)
          o[fe][fn] = mfma16(vf[fe], pf[fn], o[fe][fn]);
      __builtin_amdgcn_s_setprio(0);
    }
    __builtin_amdgcn_s_barrier();
    __builtin_amdgcn_sched_barrier(0);
  }

  // epilogue: direct 8B stores
  #pragma unroll
  for (int fn = 0; fn < 4; ++fn) {
    float inv = 1.f / lrun[fn];
    size_t rowb = (bkBase + wq0 + fn * 16 + r15) * 512 + h * 64;
    #pragma unroll
    for (int fe = 0; fe < 4; ++fe) {
      unsigned u0 = cvt_pk_bf16(o[fe][fn][0] * inv, o[fe][fn][1] * inv);
      unsigned u1 = cvt_pk_bf16(o[fe][fn][2] * inv, o[fe][fn][3] * inv);
      *(uint2*)(aout + rowb + fe * 16 + g * 4) = make_uint2(u0, u1);
    }
  }
}

// ---------- K5: LN2 (rowwise over 512), bf16 in -> bf16 out ----------
__global__ __launch_bounds__(256) void k_ln2(
    const unsigned short* __restrict__ in, const float* __restrict__ g2, const float* __restrict__ b2,
    unsigned short* __restrict__ out)
{
  int token = blockIdx.x * 4 + (threadIdx.x >> 6);
  int lane = threadIdx.x & 63;
  s16x8 v8 = *(const s16x8*)(in + (size_t)token * 512 + lane * 8);
  float vv[8]; float s = 0.f, ss = 0.f;
  #pragma unroll
  for (int i = 0; i < 8; ++i) {
    float v = bf2f((unsigned short)v8[i]); vv[i] = v; s += v; ss += v * v;
  }
  #pragma unroll
  for (int d = 1; d < 64; d <<= 1) { s += __shfl_xor(s, d); ss += __shfl_xor(ss, d); }
  float mean = s * (1.f / 512.f);
  float var = ss * (1.f / 512.f) - mean * mean;
  float rs = rsqrtf(var + 1e-5f);
  const float4 gA = *(const float4*)(g2 + lane * 8);
  const float4 gB = *(const float4*)(g2 + lane * 8 + 4);
  const float4 bA = *(const float4*)(b2 + lane * 8);
  const float4 bB = *(const float4*)(b2 + lane * 8 + 4);
  float gv[8] = {gA.x, gA.y, gA.z, gA.w, gB.x, gB.y, gB.z, gB.w};
  float bv[8] = {bA.x, bA.y, bA.z, bA.w, bB.x, bB.y, bB.z, bB.w};
  s16x8 o8;
  #pragma unroll
  for (int i = 0; i < 8; ++i)
    o8[i] = (short)f2bf((vv[i] - mean) * rs * gv[i] + bv[i]);
  *(s16x8*)(out + (size_t)token * 512 + lane * 8) = o8;
}

// ---------- host ----------
extern "C" void kernel_launch(void* const* d_in, const int* in_sizes, int n_in,
                              void* d_out, int out_size, void* d_ws, size_t ws_size,
                              hipStream_t stream)
{
  const float* x   = (const float*)d_in[0];
  const float* dtb = (const float*)d_in[1];
  const float* dhb = (const float*)d_in[2];
  const float* dwb = (const float*)d_in[3];
  const float* g1  = (const float*)d_in[4];
  const float* bb1 = (const float*)d_in[5];
  const float* wq  = (const float*)d_in[6];
  const float* wk  = (const float*)d_in[7];
  const float* wv  = (const float*)d_in[8];
  const float* wp  = (const float*)d_in[9];
  const float* g2  = (const float*)d_in[10];
  const float* bb2 = (const float*)d_in[11];
  const float* w1  = (const float*)d_in[12];
  const float* fb1 = (const float*)d_in[13];
  const float* w2  = (const float*)d_in[14];
  const float* fb2 = (const float*)d_in[15];

  char* ws = (char*)d_ws;
  unsigned short* xb   = (unsigned short*)(ws + 0);          // resid bf16 [K1..gemm1]
  unsigned short* vT   = (unsigned short*)(ws + 33554432);   // v^T bf16 [gemm0..attn]
  unsigned short* out1b= (unsigned short*)(ws + 33554432);   // proj+resid bf16 [gemm1..gemm3]
  unsigned short* qkv  = (unsigned short*)(ws + 67108864);   // q,k bf16 [gemm0..attn]; h1 [gemm2..gemm3]
  unsigned short* xn   = (unsigned short*)(ws + 117440512);  // xn; attn_out; y
  unsigned short* qkvT = (unsigned short*)(ws + 134217728);
  unsigned short* wpT  = (unsigned short*)(ws + 135790592);
  unsigned short* w1T  = (unsigned short*)(ws + 136314880);
  unsigned short* w2T  = (unsigned short*)(ws + 136839168);

  unsigned short* attn_out = xn;
  unsigned short* yb = xn;
  unsigned short* h1 = qkv;
  float* outp = (float*)d_out;

  k_gather_ln<<<1024 + 6144, 256, 0, stream>>>(x, g1, bb1, xb, xn,
      wq, wk, wv, wp, w1, w2, qkvT, wpT, w1T, w2T);
  k_gemm<0><<<dim3(128, 12), 256, 0, stream>>>(xn, qkvT, 16384, 1536, qkv, nullptr, nullptr, nullptr, vT);
  k_attn<<<512, 256, 0, stream>>>(qkv, vT, dtb, dhb, dwb, attn_out);
  k_gemm<1><<<dim3(128, 4), 256, 0, stream>>>(attn_out, wpT, 16384, 512, out1b, nullptr, nullptr, xb, nullptr);
  k_ln2<<<4096, 256, 0, stream>>>(out1b, g2, bb2, yb);
  k_gemm<2><<<dim3(128, 4), 256, 0, stream>>>(yb, w1T, 16384, 512, h1, nullptr, fb1, nullptr, nullptr);
  k_gemm<3><<<dim3(128, 4), 256, 0, stream>>>(h1, w2T, 16384, 512, nullptr, outp, fb2, out1b, nullptr);
}